// Round 3
// baseline (217.400 us; speedup 1.0000x reference)
//
#include <hip/hip_runtime.h>
#include <hip/hip_bf16.h>

typedef __bf16 bf16_t;
typedef __bf16 bf16x8 __attribute__((ext_vector_type(8)));
typedef __bf16 bf16x4 __attribute__((ext_vector_type(4)));
typedef float  f32x4  __attribute__((ext_vector_type(4)));
typedef float  f32x16 __attribute__((ext_vector_type(16)));
typedef unsigned int u32;
typedef unsigned int u32x2v __attribute__((ext_vector_type(2)));
typedef unsigned int u32x4v __attribute__((ext_vector_type(4)));

#define D_MODEL   1024
#define NQKV      3072
#define NUM_HEADS 16
#define HEAD_DIM  64
#define SEQ       2048
#define BATCH     2
#define NTOK      4096
// 0.125 * log2(e): folded into Q by rope so softmax uses exp2 directly
#define SM_SCALE_LOG2E 0.18033688011112042f
#define NEG_BIG  (-3.0e38f)

// XOR slot swizzle for LDS tiles with 128-byte rows
__device__ __forceinline__ int swz128(int row, int bytecol) {
  return row*128 + ((((bytecol>>4) ^ (row&7))<<4) | (bytecol & 15));
}

__device__ __forceinline__ void gload16(const void* g, void* l) {
  __builtin_amdgcn_global_load_lds((const __attribute__((address_space(1))) u32*)g,
                                   (__attribute__((address_space(3))) u32*)l, 16, 0, 0);
}

__device__ __forceinline__ u32 cvtpk_bf16(float a, float b) {
  u32 r;
  asm("v_cvt_pk_bf16_f32 %0, %1, %2" : "=v"(r) : "v"(a), "v"(b));
  return r;
}

// permlane32_swap: res0 = [a.lo | b.lo], res1 = [a.hi | b.hi] (dst.hi <-> src.lo)
__device__ __forceinline__ void plswap(u32 &a, u32 &b) {
#if __has_builtin(__builtin_amdgcn_permlane32_swap)
  u32x2v r = __builtin_amdgcn_permlane32_swap(a, b, false, false);
  a = r[0]; b = r[1];
#else
  u32 xa = __shfl_xor((unsigned)a, 32, 64);
  u32 xb = __shfl_xor((unsigned)b, 32, 64);
  bool hi = (threadIdx.x & 32) != 0;
  a = hi ? xb : a;
  b = hi ? b : xa;
#endif
}

// ---------------- fp32 -> bf16 conversions ----------------
__global__ void cvt_x(const float* __restrict__ in, bf16_t* __restrict__ out) {
  int i = (blockIdx.x*256 + threadIdx.x)*4;
  float4 v = *reinterpret_cast<const float4*>(in + i);
  bf16x4 o; o[0]=(bf16_t)v.x; o[1]=(bf16_t)v.y; o[2]=(bf16_t)v.z; o[3]=(bf16_t)v.w;
  *reinterpret_cast<bf16x4*>(out + i) = o;
}

__global__ void cvt_w(const float* __restrict__ wq, const float* __restrict__ wk,
                      const float* __restrict__ wv, const float* __restrict__ wo,
                      bf16_t* __restrict__ wqkv, bf16_t* __restrict__ wob) {
  const int NW = D_MODEL*D_MODEL;
  int i = (blockIdx.x*256 + threadIdx.x)*4;
  float4 v;
  if      (i <   NW) v = *reinterpret_cast<const float4*>(wq + i);
  else if (i < 2*NW) v = *reinterpret_cast<const float4*>(wk + i - NW);
  else if (i < 3*NW) v = *reinterpret_cast<const float4*>(wv + i - 2*NW);
  else               v = *reinterpret_cast<const float4*>(wo + i - 3*NW);
  bf16x4 o; o[0]=(bf16_t)v.x; o[1]=(bf16_t)v.y; o[2]=(bf16_t)v.z; o[3]=(bf16_t)v.w;
  bf16_t* dst = (i < 3*NW) ? (wqkv + i) : (wob + i - 3*NW);
  *reinterpret_cast<bf16x4*>(dst) = o;
}

// ---------------- RoPE on Q and K inside QKV buffer ----------------
__global__ void rope_qk(bf16_t* __restrict__ QKV, const int* __restrict__ pos) {
  int i = blockIdx.x*256 + threadIdx.x;
  int j = i & 31;
  int hp = (i >> 5) & 15;
  int t  = i >> 9;
  float ang = (float)pos[t & (SEQ-1)] * exp2f(-(float)j * (13.287712379549449f/32.0f));
  float sv, cv; sincosf(ang, &sv, &cv);
  size_t base = (size_t)t*NQKV + hp*64 + 2*j;
  float xe = (float)QKV[base], xo = (float)QKV[base+1];
  QKV[base]   = (bf16_t)((xe*cv - xo*sv)*SM_SCALE_LOG2E);
  QKV[base+1] = (bf16_t)((xe*sv + xo*cv)*SM_SCALE_LOG2E);
  xe = (float)QKV[base+1024]; xo = (float)QKV[base+1025];
  QKV[base+1024] = (bf16_t)(xe*cv - xo*sv);
  QKV[base+1025] = (bf16_t)(xe*sv + xo*cv);
}

// ---------------- GEMM: C[M,N] = A[M,K]*B[N,K]^T (m97-style) ----------------
template<typename OutT, bool QKV>
__global__ __launch_bounds__(256) void gemm_bt(const bf16_t* __restrict__ A,
                                               const bf16_t* __restrict__ B,
                                               OutT* __restrict__ C,
                                               bf16_t* __restrict__ Vt,
                                               int M, int N, int K) {
  __shared__ __align__(16) char lA[128*128];
  __shared__ __align__(16) char lB[128*128];
  int tid = threadIdx.x;
  int n0 = blockIdx.x*128, m0 = blockIdx.y*128;
  int wid = tid>>6, lane = tid&63;
  int wr = wid>>1, wc = wid&1;
  int lr = lane&15, lg = lane>>4;

  const bf16_t* ga = A + (size_t)(m0 + (tid>>3))*K + (tid&7)*8;
  const bf16_t* gb = B + (size_t)(n0 + (tid>>3))*K + (tid&7)*8;
  char* la = lA + tid*16;
  char* lb = lB + tid*16;

  f32x4 acc[4][4];
  #pragma unroll
  for (int a=0;a<4;a++)
    #pragma unroll
    for (int b=0;b<4;b++) acc[a][b] = (f32x4){0.f,0.f,0.f,0.f};

  for (int k0 = 0; k0 < K; k0 += 64) {
    __syncthreads();
    #pragma unroll
    for (int p=0;p<4;p++) {
      gload16(ga + (size_t)p*32*K + k0, la + p*4096);
      gload16(gb + (size_t)p*32*K + k0, lb + p*4096);
    }
    __syncthreads();
    #pragma unroll
    for (int t=0;t<2;t++) {
      bf16x8 af[4], bfr[4];
      #pragma unroll
      for (int mi=0;mi<4;mi++)
        af[mi] = *reinterpret_cast<const bf16x8*>(lA + (wr*64+mi*16+lr)*128 + t*64 + lg*16);
      #pragma unroll
      for (int ni=0;ni<4;ni++)
        bfr[ni] = *reinterpret_cast<const bf16x8*>(lB + (wc*64+ni*16+lr)*128 + t*64 + lg*16);
      #pragma unroll
      for (int mi=0;mi<4;mi++)
        #pragma unroll
        for (int ni=0;ni<4;ni++)
          acc[mi][ni] = __builtin_amdgcn_mfma_f32_16x16x32_bf16(af[mi], bfr[ni], acc[mi][ni], 0, 0, 0);
    }
  }

  if (!QKV || n0 < 2*D_MODEL) {
    #pragma unroll
    for (int mi=0;mi<4;mi++)
      #pragma unroll
      for (int ni=0;ni<4;ni++)
        #pragma unroll
        for (int r=0;r<4;r++) {
          int m = m0 + wr*64 + mi*16 + lg*4 + r;
          int n = n0 + wc*64 + ni*16 + lr;
          C[(size_t)m*N + n] = (OutT)acc[mi][ni][r];
        }
  } else {
    #pragma unroll
    for (int mi=0;mi<4;mi++)
      #pragma unroll
      for (int ni=0;ni<4;ni++)
        #pragma unroll
        for (int r=0;r<4;r++) {
          int m = m0 + wr*64 + mi*16 + lg*4 + r;
          int nl = n0 + wc*64 + ni*16 + lr - 2*D_MODEL;
          int h = nl >> 6, d = nl & 63;
          int bb = m >> 11, s = m & (SEQ-1);
          Vt[(((size_t)(bb*16 + h)*64 + d) << 11) + s] = (bf16_t)acc[mi][ni][r];
        }
  }
}

// ---------------- Flash causal attention, swapped-QK^T 32x32 ----------------
// grid (8, B*H). block = 4 waves; wave w owns 32 q-rows; QBLK=128 per q-block;
// block handles q-blocks {bx, 15-bx} (balanced 36 tile-iters).
// Per KV tile (64 keys): S^T = mfma32(K, Q^T) -> lane-local softmax ->
// cvt_pk+permlane32_swap -> O^T += mfma32(V^T, P^T). KV double-buffered in LDS
// via global_load_lds with inverse-swizzled global source.
__global__ __launch_bounds__(256) void attn2(const bf16_t* __restrict__ QKV,
                                             const bf16_t* __restrict__ Vt,
                                             bf16_t* __restrict__ Of) {
  __shared__ __align__(16) char sK[2][64*128];
  __shared__ __align__(16) char sV[2][64*128];

  int bh = blockIdx.y;
  int b = bh >> 4, h = bh & 15;
  int tid = threadIdx.x, w = tid>>6, lane = tid&63;
  int q32 = lane & 31, hi = lane >> 5;

  const bf16_t* Kb = QKV + D_MODEL;
  const bf16_t* Vb = Vt + (size_t)bh*64*SEQ;

  // staging constants: wave w stages rows 16w..16w+15 (2 chunks of 8 rows)
  int rsub = lane >> 3;                 // 0..7 within chunk
  int sg   = (lane&7) ^ rsub;           // inverse-swizzled slot

  for (int half = 0; half < 2; ++half) {
    int qb  = half ? 15 - (int)blockIdx.x : (int)blockIdx.x;
    int qw0 = qb*128 + w*32;
    int nt  = 2*qb + 2;
    int tlast = (qw0 + 31) >> 6;
    int qg = qw0 + q32;

    // Q fragments: lane q32 needs Q[q][dstep*16 + hi*8 .. +8]
    bf16x8 qf[4];
    const bf16_t* qrow = QKV + (size_t)(b*SEQ + qw0 + q32)*NQKV + h*64 + hi*8;
    #pragma unroll
    for (int d=0; d<4; d++) qf[d] = *reinterpret_cast<const bf16x8*>(qrow + d*16);

    f32x16 O0 = (f32x16)0.0f, O1 = (f32x16)0.0f;
    float mrun = NEG_BIG, lrun = 0.f;

    // stage tile 0 into buf 0
    {
      int r0 = 16*w, k0s = 0;
      #pragma unroll
      for (int c=0;c<2;c++) {
        int rr = r0 + 8*c + rsub;
        gload16(Kb + (size_t)(b*SEQ + k0s + rr)*NQKV + h*64 + sg*8,
                sK[0] + (r0 + 8*c)*128 + lane*16);
        gload16(Vb + (size_t)rr*SEQ + k0s + sg*8,
                sV[0] + (r0 + 8*c)*128 + lane*16);
      }
    }
    __syncthreads();

    for (int ti = 0; ti < nt; ++ti) {
      int cur = ti & 1;
      // prefetch next tile into other buffer (hides HBM latency under compute)
      if (ti + 1 < nt) {
        int r0 = 16*w, k0s = (ti+1)*64;
        #pragma unroll
        for (int c=0;c<2;c++) {
          int rr = r0 + 8*c + rsub;
          gload16(Kb + (size_t)(b*SEQ + k0s + rr)*NQKV + h*64 + sg*8,
                  sK[cur^1] + (r0 + 8*c)*128 + lane*16);
          gload16(Vb + (size_t)rr*SEQ + k0s + sg*8,
                  sV[cur^1] + (r0 + 8*c)*128 + lane*16);
        }
      }

      if (ti <= tlast) {
        int k0 = ti*64;
        bool diag = (ti == tlast);

        // S^T = K * Q^T : p0 = keys 0..31 (rows), p1 = keys 32..63
        f32x16 p0 = (f32x16)0.0f, p1 = (f32x16)0.0f;
        #pragma unroll
        for (int ds=0; ds<4; ds++) {
          bf16x8 k0f = *reinterpret_cast<const bf16x8*>(sK[cur] + swz128(q32,    ds*32 + hi*16));
          bf16x8 k1f = *reinterpret_cast<const bf16x8*>(sK[cur] + swz128(32+q32, ds*32 + hi*16));
          p0 = __builtin_amdgcn_mfma_f32_32x32x16_bf16(k0f, qf[ds], p0, 0, 0, 0);
          p1 = __builtin_amdgcn_mfma_f32_32x32x16_bf16(k1f, qf[ds], p1, 0, 0, 0);
        }

        // causal mask (diagonal tile only) + row max (lane-local 32 + 1 shfl)
        float mloc = NEG_BIG;
        #pragma unroll
        for (int r=0; r<16; r++) {
          if (diag) {
            int kg = k0 + (r&3) + 8*(r>>2) + 4*hi;
            if (kg      > qg) p0[r] = NEG_BIG;
            if (kg + 32 > qg) p1[r] = NEG_BIG;
          }
          mloc = fmaxf(mloc, fmaxf(p0[r], p1[r]));
        }
        float mt   = fmaxf(mloc, __shfl_xor(mloc, 32, 64));
        float mnew = fmaxf(mrun, mt);
        float alpha = exp2f(mrun - mnew);
        float sloc = 0.f;
        #pragma unroll
        for (int r=0; r<16; r++) {
          p0[r] = exp2f(p0[r] - mnew); sloc += p0[r];
          p1[r] = exp2f(p1[r] - mnew); sloc += p1[r];
        }
        float stot = sloc + __shfl_xor(sloc, 32, 64);
        lrun = lrun*alpha + stot;
        mrun = mnew;
        O0 *= alpha; O1 *= alpha;

        // pack P -> bf16 and redistribute halves (T12)
        u32 pk0[8], pk1[8];
        #pragma unroll
        for (int i2=0; i2<8; i2++) {
          pk0[i2] = cvtpk_bf16(p0[2*i2], p0[2*i2+1]);
          pk1[i2] = cvtpk_bf16(p1[2*i2], p1[2*i2+1]);
        }
        plswap(pk0[0], pk0[2]); plswap(pk0[1], pk0[3]);
        plswap(pk0[4], pk0[6]); plswap(pk0[5], pk0[7]);
        plswap(pk1[0], pk1[2]); plswap(pk1[1], pk1[3]);
        plswap(pk1[4], pk1[6]); plswap(pk1[5], pk1[7]);

        bf16x8 pa[4];
        pa[0] = __builtin_bit_cast(bf16x8, (u32x4v){pk0[0],pk0[1],pk0[2],pk0[3]});
        pa[1] = __builtin_bit_cast(bf16x8, (u32x4v){pk0[4],pk0[5],pk0[6],pk0[7]});
        pa[2] = __builtin_bit_cast(bf16x8, (u32x4v){pk1[0],pk1[1],pk1[2],pk1[3]});
        pa[3] = __builtin_bit_cast(bf16x8, (u32x4v){pk1[4],pk1[5],pk1[6],pk1[7]});

        // O^T += V^T * P^T  (A rows = dims, B cols = q)
        #pragma unroll
        for (int ks=0; ks<4; ks++) {
          bf16x8 v0 = *reinterpret_cast<const bf16x8*>(sV[cur] + swz128(q32,    ks*32 + hi*16));
          bf16x8 v1 = *reinterpret_cast<const bf16x8*>(sV[cur] + swz128(32+q32, ks*32 + hi*16));
          O0 = __builtin_amdgcn_mfma_f32_32x32x16_bf16(v0, pa[ks], O0, 0, 0, 0);
          O1 = __builtin_amdgcn_mfma_f32_32x32x16_bf16(v1, pa[ks], O1, 0, 0, 0);
        }
      }
      __syncthreads();   // drains prefetch vmcnt + joins waves
    }

    // epilogue: O^T regs -> O[q][d], packed 8B stores
    float linv = 1.0f / lrun;
    bf16_t* orow = Of + (size_t)(b*SEQ + qw0 + q32)*D_MODEL + h*64;
    #pragma unroll
    for (int rg=0; rg<4; rg++) {
      int d0 = 8*rg + 4*hi;
      u32 a0 = cvtpk_bf16(O0[4*rg]*linv,   O0[4*rg+1]*linv);
      u32 a1 = cvtpk_bf16(O0[4*rg+2]*linv, O0[4*rg+3]*linv);
      *reinterpret_cast<u32x2v*>(orow + d0) = (u32x2v){a0, a1};
      u32 b0 = cvtpk_bf16(O1[4*rg]*linv,   O1[4*rg+1]*linv);
      u32 b1 = cvtpk_bf16(O1[4*rg+2]*linv, O1[4*rg+3]*linv);
      *reinterpret_cast<u32x2v*>(orow + 32 + d0) = (u32x2v){b0, b1};
    }
  }
}

// ---------------- launch ----------------
extern "C" void kernel_launch(void* const* d_in, const int* in_sizes, int n_in,
                              void* d_out, int out_size, void* d_ws, size_t ws_size,
                              hipStream_t stream) {
  const float* x   = (const float*)d_in[0];
  const int*   pos = (const int*)  d_in[1];
  const float* wq  = (const float*)d_in[2];
  const float* wk  = (const float*)d_in[3];
  const float* wv  = (const float*)d_in[4];
  const float* wo  = (const float*)d_in[5];
  float* out = (float*)d_out;

  char* ws = (char*)d_ws;
  bf16_t* xb   = (bf16_t*)(ws);                 // 8 MB; reused as Of after attn
  bf16_t* wqkv = (bf16_t*)(ws + ( 8u<<20));     // 6 MB
  bf16_t* wob  = (bf16_t*)(ws + (14u<<20));     // 2 MB
  bf16_t* QKV  = (bf16_t*)(ws + (16u<<20));     // 24 MB
  bf16_t* Vtb  = (bf16_t*)(ws + (40u<<20));     // 8 MB
  bf16_t* Of   = xb;

  cvt_x<<<NTOK*D_MODEL/1024, 256, 0, stream>>>(x, xb);
  cvt_w<<<4*D_MODEL*D_MODEL/1024, 256, 0, stream>>>(wq, wk, wv, wo, wqkv, wob);

  dim3 gqkv(NQKV/128, NTOK/128);
  gemm_bt<bf16_t, true><<<gqkv, 256, 0, stream>>>(xb, wqkv, QKV, Vtb, NTOK, NQKV, D_MODEL);

  rope_qk<<<NTOK*NUM_HEADS*32/256, 256, 0, stream>>>(QKV, pos);

  dim3 gattn(8, BATCH*NUM_HEADS);
  attn2<<<gattn, 256, 0, stream>>>(QKV, Vtb, Of);

  dim3 gout(D_MODEL/128, NTOK/128);
  gemm_bt<float, false><<<gout, 256, 0, stream>>>(Of, wob, out, nullptr, NTOK, D_MODEL, D_MODEL);
}

// Round 4
// 193.530 us; speedup vs baseline: 1.1233x; 1.1233x over previous
//
#include <hip/hip_runtime.h>
#include <hip/hip_bf16.h>

typedef __bf16 bf16_t;
typedef __bf16 bf16x8 __attribute__((ext_vector_type(8)));
typedef __bf16 bf16x4 __attribute__((ext_vector_type(4)));
typedef float  f32x4  __attribute__((ext_vector_type(4)));
typedef float  f32x16 __attribute__((ext_vector_type(16)));
typedef unsigned int u32;
typedef unsigned int u32x2v __attribute__((ext_vector_type(2)));
typedef unsigned int u32x4v __attribute__((ext_vector_type(4)));

#define D_MODEL   1024
#define NQKV      3072
#define NUM_HEADS 16
#define HEAD_DIM  64
#define SEQ       2048
#define BATCH     2
#define NTOK      4096
// 0.125 * log2(e): folded into Q by rope so softmax uses exp2 directly
#define SM_SCALE_LOG2E 0.18033688011112042f
#define NEG_BIG  (-3.0e38f)

// XOR slot swizzle for LDS tiles with 128-byte rows
__device__ __forceinline__ int swz128(int row, int bytecol) {
  return row*128 + ((((bytecol>>4) ^ (row&7))<<4) | (bytecol & 15));
}

__device__ __forceinline__ void gload16(const void* g, void* l) {
  __builtin_amdgcn_global_load_lds((const __attribute__((address_space(1))) u32*)g,
                                   (__attribute__((address_space(3))) u32*)l, 16, 0, 0);
}

__device__ __forceinline__ u32 cvtpk_bf16(float a, float b) {
  u32 r;
  asm("v_cvt_pk_bf16_f32 %0, %1, %2" : "=v"(r) : "v"(a), "v"(b));
  return r;
}

// permlane32_swap: res0 = [a.lo | b.lo], res1 = [a.hi | b.hi]
__device__ __forceinline__ void plswap(u32 &a, u32 &b) {
#if __has_builtin(__builtin_amdgcn_permlane32_swap)
  u32x2v r = __builtin_amdgcn_permlane32_swap(a, b, false, false);
  a = r[0]; b = r[1];
#else
  u32 xa = __shfl_xor((unsigned)a, 32, 64);
  u32 xb = __shfl_xor((unsigned)b, 32, 64);
  bool hi = (threadIdx.x & 32) != 0;
  a = hi ? xb : a;
  b = hi ? b : xa;
#endif
}

// ---------------- fp32 -> bf16 conversions ----------------
__global__ void cvt_x(const float* __restrict__ in, bf16_t* __restrict__ out) {
  int i = (blockIdx.x*256 + threadIdx.x)*4;
  float4 v = *reinterpret_cast<const float4*>(in + i);
  bf16x4 o; o[0]=(bf16_t)v.x; o[1]=(bf16_t)v.y; o[2]=(bf16_t)v.z; o[3]=(bf16_t)v.w;
  *reinterpret_cast<bf16x4*>(out + i) = o;
}

__global__ void cvt_w(const float* __restrict__ wq, const float* __restrict__ wk,
                      const float* __restrict__ wv, const float* __restrict__ wo,
                      bf16_t* __restrict__ wqkv, bf16_t* __restrict__ wob) {
  const int NW = D_MODEL*D_MODEL;
  int i = (blockIdx.x*256 + threadIdx.x)*4;
  float4 v;
  if      (i <   NW) v = *reinterpret_cast<const float4*>(wq + i);
  else if (i < 2*NW) v = *reinterpret_cast<const float4*>(wk + i - NW);
  else if (i < 3*NW) v = *reinterpret_cast<const float4*>(wv + i - 2*NW);
  else               v = *reinterpret_cast<const float4*>(wo + i - 3*NW);
  bf16x4 o; o[0]=(bf16_t)v.x; o[1]=(bf16_t)v.y; o[2]=(bf16_t)v.z; o[3]=(bf16_t)v.w;
  bf16_t* dst = (i < 3*NW) ? (wqkv + i) : (wob + i - 3*NW);
  *reinterpret_cast<bf16x4*>(dst) = o;
}

// ---------------- RoPE on Q and K inside QKV buffer ----------------
__global__ void rope_qk(bf16_t* __restrict__ QKV, const int* __restrict__ pos) {
  int i = blockIdx.x*256 + threadIdx.x;
  int j = i & 31;
  int hp = (i >> 5) & 15;
  int t  = i >> 9;
  float ang = (float)pos[t & (SEQ-1)] * exp2f(-(float)j * (13.287712379549449f/32.0f));
  float sv, cv; sincosf(ang, &sv, &cv);
  size_t base = (size_t)t*NQKV + hp*64 + 2*j;
  float xe = (float)QKV[base], xo = (float)QKV[base+1];
  QKV[base]   = (bf16_t)((xe*cv - xo*sv)*SM_SCALE_LOG2E);
  QKV[base+1] = (bf16_t)((xe*sv + xo*cv)*SM_SCALE_LOG2E);
  xe = (float)QKV[base+1024]; xo = (float)QKV[base+1025];
  QKV[base+1024] = (bf16_t)(xe*cv - xo*sv);
  QKV[base+1025] = (bf16_t)(xe*sv + xo*cv);
}

// ---------------- GEMM: C[M,N] = A[M,K]*B[N,K]^T (m97-style) ----------------
template<typename OutT, bool QKV>
__global__ __launch_bounds__(256) void gemm_bt(const bf16_t* __restrict__ A,
                                               const bf16_t* __restrict__ B,
                                               OutT* __restrict__ C,
                                               bf16_t* __restrict__ Vt,
                                               int M, int N, int K) {
  __shared__ __align__(16) char lA[128*128];
  __shared__ __align__(16) char lB[128*128];
  int tid = threadIdx.x;
  int n0 = blockIdx.x*128, m0 = blockIdx.y*128;
  int wid = tid>>6, lane = tid&63;
  int wr = wid>>1, wc = wid&1;
  int lr = lane&15, lg = lane>>4;

  const bf16_t* ga = A + (size_t)(m0 + (tid>>3))*K + (tid&7)*8;
  const bf16_t* gb = B + (size_t)(n0 + (tid>>3))*K + (tid&7)*8;
  char* la = lA + tid*16;
  char* lb = lB + tid*16;

  f32x4 acc[4][4];
  #pragma unroll
  for (int a=0;a<4;a++)
    #pragma unroll
    for (int b=0;b<4;b++) acc[a][b] = (f32x4){0.f,0.f,0.f,0.f};

  for (int k0 = 0; k0 < K; k0 += 64) {
    __syncthreads();
    #pragma unroll
    for (int p=0;p<4;p++) {
      gload16(ga + (size_t)p*32*K + k0, la + p*4096);
      gload16(gb + (size_t)p*32*K + k0, lb + p*4096);
    }
    __syncthreads();
    #pragma unroll
    for (int t=0;t<2;t++) {
      bf16x8 af[4], bfr[4];
      #pragma unroll
      for (int mi=0;mi<4;mi++)
        af[mi] = *reinterpret_cast<const bf16x8*>(lA + (wr*64+mi*16+lr)*128 + t*64 + lg*16);
      #pragma unroll
      for (int ni=0;ni<4;ni++)
        bfr[ni] = *reinterpret_cast<const bf16x8*>(lB + (wc*64+ni*16+lr)*128 + t*64 + lg*16);
      #pragma unroll
      for (int mi=0;mi<4;mi++)
        #pragma unroll
        for (int ni=0;ni<4;ni++)
          acc[mi][ni] = __builtin_amdgcn_mfma_f32_16x16x32_bf16(af[mi], bfr[ni], acc[mi][ni], 0, 0, 0);
    }
  }

  if (!QKV || n0 < 2*D_MODEL) {
    #pragma unroll
    for (int mi=0;mi<4;mi++)
      #pragma unroll
      for (int ni=0;ni<4;ni++)
        #pragma unroll
        for (int r=0;r<4;r++) {
          int m = m0 + wr*64 + mi*16 + lg*4 + r;
          int n = n0 + wc*64 + ni*16 + lr;
          C[(size_t)m*N + n] = (OutT)acc[mi][ni][r];
        }
  } else {
    #pragma unroll
    for (int mi=0;mi<4;mi++)
      #pragma unroll
      for (int ni=0;ni<4;ni++)
        #pragma unroll
        for (int r=0;r<4;r++) {
          int m = m0 + wr*64 + mi*16 + lg*4 + r;
          int nl = n0 + wc*64 + ni*16 + lr - 2*D_MODEL;
          int h = nl >> 6, d = nl & 63;
          int bb = m >> 11, s = m & (SEQ-1);
          Vt[(((size_t)(bb*16 + h)*64 + d) << 11) + s] = (bf16_t)acc[mi][ni][r];
        }
  }
}

// ---------------- Flash causal attention, swapped-QK^T 32x32 ----------------
// grid (32, B*H), block = 2 waves (128 thr). Wave w owns 32 q-rows of a 64-row
// q-block; qb = 31-bx (longest first). Per KV tile (64 keys):
// S^T = mfma32(K, Q^T) -> lane-local softmax -> cvt_pk+permlane32_swap ->
// O^T += mfma32(V^T, P^T). KV double-buffered via global_load_lds with
// inverse-swizzled global source.
__global__ __launch_bounds__(128, 2) void attn3(const bf16_t* __restrict__ QKV,
                                                const bf16_t* __restrict__ Vt,
                                                bf16_t* __restrict__ Of) {
  __shared__ __align__(16) char sK[2][64*128];
  __shared__ __align__(16) char sV[2][64*128];

  int bh = blockIdx.y;
  int b = bh >> 4, h = bh & 15;
  int tid = threadIdx.x, w = tid>>6, lane = tid&63;
  int q32 = lane & 31, hi = lane >> 5;

  const bf16_t* Kb = QKV + D_MODEL;
  const bf16_t* Vb = Vt + (size_t)bh*64*SEQ;

  int rsub = lane >> 3;                 // 0..7 within 8-row chunk
  int sg   = (lane&7) ^ rsub;           // inverse-swizzled slot

  int qb  = 31 - (int)blockIdx.x;       // longest blocks dispatch first
  int qw0 = qb*64 + w*32;
  int nt  = qb + 1;
  int qg  = qw0 + q32;

  // Q fragments: lane q32 = column q; qf[ds] covers dims ds*16 + hi*8 ..+8
  bf16x8 qf[4];
  const bf16_t* qrow = QKV + (size_t)(b*SEQ + qw0 + q32)*NQKV + h*64 + hi*8;
  #pragma unroll
  for (int d=0; d<4; d++) qf[d] = *reinterpret_cast<const bf16x8*>(qrow + d*16);

  f32x16 O0 = (f32x16)0.0f, O1 = (f32x16)0.0f;
  float mrun = NEG_BIG, lrun = 0.f;

  // stage tile 0 into buf 0: wave w stages rows w*32..w*32+31 of K and V
  #pragma unroll
  for (int c=0;c<4;c++) {
    int rr = w*32 + 8*c + rsub;
    gload16(Kb + (size_t)(b*SEQ + rr)*NQKV + h*64 + sg*8,
            sK[0] + (w*32 + 8*c)*128 + lane*16);
    gload16(Vb + (size_t)rr*SEQ + sg*8,
            sV[0] + (w*32 + 8*c)*128 + lane*16);
  }
  __syncthreads();

  for (int ti = 0; ti < nt; ++ti) {
    int cur = ti & 1;
    if (ti + 1 < nt) {
      int k0s = (ti+1)*64;
      #pragma unroll
      for (int c=0;c<4;c++) {
        int rr = w*32 + 8*c + rsub;
        gload16(Kb + (size_t)(b*SEQ + k0s + rr)*NQKV + h*64 + sg*8,
                sK[cur^1] + (w*32 + 8*c)*128 + lane*16);
        gload16(Vb + (size_t)rr*SEQ + k0s + sg*8,
                sV[cur^1] + (w*32 + 8*c)*128 + lane*16);
      }
    }

    int k0 = ti*64;
    bool diag = (ti == nt-1);

    // S^T = K * Q^T : p0 = keys 0..31, p1 = keys 32..63
    f32x16 p0 = (f32x16)0.0f, p1 = (f32x16)0.0f;
    #pragma unroll
    for (int ds=0; ds<4; ds++) {
      bf16x8 k0f = *reinterpret_cast<const bf16x8*>(sK[cur] + swz128(q32,    ds*32 + hi*16));
      bf16x8 k1f = *reinterpret_cast<const bf16x8*>(sK[cur] + swz128(32+q32, ds*32 + hi*16));
      p0 = __builtin_amdgcn_mfma_f32_32x32x16_bf16(k0f, qf[ds], p0, 0, 0, 0);
      p1 = __builtin_amdgcn_mfma_f32_32x32x16_bf16(k1f, qf[ds], p1, 0, 0, 0);
    }

    // causal mask (diagonal tile only) + row max (lane-local + 1 shfl)
    float mloc = NEG_BIG;
    #pragma unroll
    for (int r=0; r<16; r++) {
      if (diag) {
        int kg = k0 + (r&3) + 8*(r>>2) + 4*hi;
        if (kg      > qg) p0[r] = NEG_BIG;
        if (kg + 32 > qg) p1[r] = NEG_BIG;
      }
      mloc = fmaxf(mloc, fmaxf(p0[r], p1[r]));
    }
    float mt   = fmaxf(mloc, __shfl_xor(mloc, 32, 64));
    float mnew = fmaxf(mrun, mt);
    float alpha = exp2f(mrun - mnew);
    float sloc = 0.f;
    #pragma unroll
    for (int r=0; r<16; r++) {
      p0[r] = exp2f(p0[r] - mnew); sloc += p0[r];
      p1[r] = exp2f(p1[r] - mnew); sloc += p1[r];
    }
    float stot = sloc + __shfl_xor(sloc, 32, 64);
    lrun = lrun*alpha + stot;
    mrun = mnew;
    O0 *= alpha; O1 *= alpha;

    // pack P -> bf16 and redistribute halves (T12)
    u32 pk0[8], pk1[8];
    #pragma unroll
    for (int i2=0; i2<8; i2++) {
      pk0[i2] = cvtpk_bf16(p0[2*i2], p0[2*i2+1]);
      pk1[i2] = cvtpk_bf16(p1[2*i2], p1[2*i2+1]);
    }
    plswap(pk0[0], pk0[2]); plswap(pk0[1], pk0[3]);
    plswap(pk0[4], pk0[6]); plswap(pk0[5], pk0[7]);
    plswap(pk1[0], pk1[2]); plswap(pk1[1], pk1[3]);
    plswap(pk1[4], pk1[6]); plswap(pk1[5], pk1[7]);

    bf16x8 pa[4];
    pa[0] = __builtin_bit_cast(bf16x8, (u32x4v){pk0[0],pk0[1],pk0[2],pk0[3]});
    pa[1] = __builtin_bit_cast(bf16x8, (u32x4v){pk0[4],pk0[5],pk0[6],pk0[7]});
    pa[2] = __builtin_bit_cast(bf16x8, (u32x4v){pk1[0],pk1[1],pk1[2],pk1[3]});
    pa[3] = __builtin_bit_cast(bf16x8, (u32x4v){pk1[4],pk1[5],pk1[6],pk1[7]});

    // O^T += V^T * P^T
    #pragma unroll
    for (int ks=0; ks<4; ks++) {
      bf16x8 v0 = *reinterpret_cast<const bf16x8*>(sV[cur] + swz128(q32,    ks*32 + hi*16));
      bf16x8 v1 = *reinterpret_cast<const bf16x8*>(sV[cur] + swz128(32+q32, ks*32 + hi*16));
      O0 = __builtin_amdgcn_mfma_f32_32x32x16_bf16(v0, pa[ks], O0, 0, 0, 0);
      O1 = __builtin_amdgcn_mfma_f32_32x32x16_bf16(v1, pa[ks], O1, 0, 0, 0);
    }

    __syncthreads();   // drains prefetch vmcnt + joins waves
  }

  // epilogue: O^T regs -> O[q][d], packed 8B stores
  float linv = 1.0f / lrun;
  bf16_t* orow = Of + (size_t)(b*SEQ + qw0 + q32)*D_MODEL + h*64;
  #pragma unroll
  for (int rg=0; rg<4; rg++) {
    int d0 = 8*rg + 4*hi;
    u32 a0 = cvtpk_bf16(O0[4*rg]*linv,   O0[4*rg+1]*linv);
    u32 a1 = cvtpk_bf16(O0[4*rg+2]*linv, O0[4*rg+3]*linv);
    *reinterpret_cast<u32x2v*>(orow + d0) = (u32x2v){a0, a1};
    u32 b0 = cvtpk_bf16(O1[4*rg]*linv,   O1[4*rg+1]*linv);
    u32 b1 = cvtpk_bf16(O1[4*rg+2]*linv, O1[4*rg+3]*linv);
    *reinterpret_cast<u32x2v*>(orow + 32 + d0) = (u32x2v){b0, b1};
  }
}

// ---------------- launch ----------------
extern "C" void kernel_launch(void* const* d_in, const int* in_sizes, int n_in,
                              void* d_out, int out_size, void* d_ws, size_t ws_size,
                              hipStream_t stream) {
  const float* x   = (const float*)d_in[0];
  const int*   pos = (const int*)  d_in[1];
  const float* wq  = (const float*)d_in[2];
  const float* wk  = (const float*)d_in[3];
  const float* wv  = (const float*)d_in[4];
  const float* wo  = (const float*)d_in[5];
  float* out = (float*)d_out;

  char* ws = (char*)d_ws;
  bf16_t* xb   = (bf16_t*)(ws);                 // 8 MB; reused as Of after attn
  bf16_t* wqkv = (bf16_t*)(ws + ( 8u<<20));     // 6 MB
  bf16_t* wob  = (bf16_t*)(ws + (14u<<20));     // 2 MB
  bf16_t* QKV  = (bf16_t*)(ws + (16u<<20));     // 24 MB
  bf16_t* Vtb  = (bf16_t*)(ws + (40u<<20));     // 8 MB
  bf16_t* Of   = xb;

  cvt_x<<<NTOK*D_MODEL/1024, 256, 0, stream>>>(x, xb);
  cvt_w<<<4*D_MODEL*D_MODEL/1024, 256, 0, stream>>>(wq, wk, wv, wo, wqkv, wob);

  dim3 gqkv(NQKV/128, NTOK/128);
  gemm_bt<bf16_t, true><<<gqkv, 256, 0, stream>>>(xb, wqkv, QKV, Vtb, NTOK, NQKV, D_MODEL);

  rope_qk<<<NTOK*NUM_HEADS*32/256, 256, 0, stream>>>(QKV, pos);

  dim3 gattn(32, BATCH*NUM_HEADS);
  attn3<<<gattn, 128, 0, stream>>>(QKV, Vtb, Of);

  dim3 gout(D_MODEL/128, NTOK/128);
  gemm_bt<float, false><<<gout, 256, 0, stream>>>(Of, wob, out, nullptr, NTOK, D_MODEL, D_MODEL);
}

// Round 5
// 173.860 us; speedup vs baseline: 1.2504x; 1.1131x over previous
//
#include <hip/hip_runtime.h>
#include <hip/hip_bf16.h>

typedef __bf16 bf16_t;
typedef __bf16 bf16x8 __attribute__((ext_vector_type(8)));
typedef __bf16 bf16x4 __attribute__((ext_vector_type(4)));
typedef float  f32x4  __attribute__((ext_vector_type(4)));
typedef float  f32x16 __attribute__((ext_vector_type(16)));
typedef unsigned int u32;
typedef unsigned int u32x2v __attribute__((ext_vector_type(2)));
typedef unsigned int u32x4v __attribute__((ext_vector_type(4)));

#define D_MODEL   1024
#define NQKV      3072
#define NUM_HEADS 16
#define HEAD_DIM  64
#define SEQ       2048
#define BATCH     2
#define NTOK      4096
// 0.125 * log2(e): folded into Q by rope so softmax uses exp2 directly
#define SM_SCALE_LOG2E 0.18033688011112042f
#define NEG_BIG  (-3.0e38f)

// XOR slot swizzle for LDS tiles with 128-byte rows
__device__ __forceinline__ int swz128(int row, int bytecol) {
  return row*128 + ((((bytecol>>4) ^ (row&7))<<4) | (bytecol & 15));
}

__device__ __forceinline__ void gload16(const void* g, void* l) {
  __builtin_amdgcn_global_load_lds((const __attribute__((address_space(1))) u32*)g,
                                   (__attribute__((address_space(3))) u32*)l, 16, 0, 0);
}

__device__ __forceinline__ u32 cvtpk_bf16(float a, float b) {
  u32 r;
  asm("v_cvt_pk_bf16_f32 %0, %1, %2" : "=v"(r) : "v"(a), "v"(b));
  return r;
}

// permlane32_swap: res0 = [a.lo | b.lo], res1 = [a.hi | b.hi]
__device__ __forceinline__ void plswap(u32 &a, u32 &b) {
#if __has_builtin(__builtin_amdgcn_permlane32_swap)
  u32x2v r = __builtin_amdgcn_permlane32_swap(a, b, false, false);
  a = r[0]; b = r[1];
#else
  u32 xa = __shfl_xor((unsigned)a, 32, 64);
  u32 xb = __shfl_xor((unsigned)b, 32, 64);
  bool hi = (threadIdx.x & 32) != 0;
  a = hi ? xb : a;
  b = hi ? b : xa;
#endif
}

// ---------------- fp32 -> bf16 conversions ----------------
__global__ void cvt_x(const float* __restrict__ in, bf16_t* __restrict__ out) {
  int i = (blockIdx.x*256 + threadIdx.x)*4;
  float4 v = *reinterpret_cast<const float4*>(in + i);
  bf16x4 o; o[0]=(bf16_t)v.x; o[1]=(bf16_t)v.y; o[2]=(bf16_t)v.z; o[3]=(bf16_t)v.w;
  *reinterpret_cast<bf16x4*>(out + i) = o;
}

__global__ void cvt_w(const float* __restrict__ wq, const float* __restrict__ wk,
                      const float* __restrict__ wv, const float* __restrict__ wo,
                      bf16_t* __restrict__ wqkv, bf16_t* __restrict__ wob) {
  const int NW = D_MODEL*D_MODEL;
  int i = (blockIdx.x*256 + threadIdx.x)*4;
  float4 v;
  if      (i <   NW) v = *reinterpret_cast<const float4*>(wq + i);
  else if (i < 2*NW) v = *reinterpret_cast<const float4*>(wk + i - NW);
  else if (i < 3*NW) v = *reinterpret_cast<const float4*>(wv + i - 2*NW);
  else               v = *reinterpret_cast<const float4*>(wo + i - 3*NW);
  bf16x4 o; o[0]=(bf16_t)v.x; o[1]=(bf16_t)v.y; o[2]=(bf16_t)v.z; o[3]=(bf16_t)v.w;
  bf16_t* dst = (i < 3*NW) ? (wqkv + i) : (wob + i - 3*NW);
  *reinterpret_cast<bf16x4*>(dst) = o;
}

// ---------------- RoPE on Q and K inside QKV buffer ----------------
__global__ void rope_qk(bf16_t* __restrict__ QKV, const int* __restrict__ pos) {
  int i = blockIdx.x*256 + threadIdx.x;
  int j = i & 31;
  int hp = (i >> 5) & 15;
  int t  = i >> 9;
  float ang = (float)pos[t & (SEQ-1)] * exp2f(-(float)j * (13.287712379549449f/32.0f));
  float sv, cv; sincosf(ang, &sv, &cv);
  size_t base = (size_t)t*NQKV + hp*64 + 2*j;
  float xe = (float)QKV[base], xo = (float)QKV[base+1];
  QKV[base]   = (bf16_t)((xe*cv - xo*sv)*SM_SCALE_LOG2E);
  QKV[base+1] = (bf16_t)((xe*sv + xo*cv)*SM_SCALE_LOG2E);
  xe = (float)QKV[base+1024]; xo = (float)QKV[base+1025];
  QKV[base+1024] = (bf16_t)(xe*cv - xo*sv);
  QKV[base+1025] = (bf16_t)(xe*sv + xo*cv);
}

// ---------------- GEMM: C[M,N] = A[M,K]*B[N,K]^T (m97-style) ----------------
template<typename OutT, bool QKV>
__global__ __launch_bounds__(256) void gemm_bt(const bf16_t* __restrict__ A,
                                               const bf16_t* __restrict__ B,
                                               OutT* __restrict__ C,
                                               bf16_t* __restrict__ Vt,
                                               int M, int N, int K) {
  __shared__ __align__(16) char lA[128*128];
  __shared__ __align__(16) char lB[128*128];
  int tid = threadIdx.x;
  int n0 = blockIdx.x*128, m0 = blockIdx.y*128;
  int wid = tid>>6, lane = tid&63;
  int wr = wid>>1, wc = wid&1;
  int lr = lane&15, lg = lane>>4;

  const bf16_t* ga = A + (size_t)(m0 + (tid>>3))*K + (tid&7)*8;
  const bf16_t* gb = B + (size_t)(n0 + (tid>>3))*K + (tid&7)*8;
  char* la = lA + tid*16;
  char* lb = lB + tid*16;

  f32x4 acc[4][4];
  #pragma unroll
  for (int a=0;a<4;a++)
    #pragma unroll
    for (int b=0;b<4;b++) acc[a][b] = (f32x4){0.f,0.f,0.f,0.f};

  for (int k0 = 0; k0 < K; k0 += 64) {
    __syncthreads();
    #pragma unroll
    for (int p=0;p<4;p++) {
      gload16(ga + (size_t)p*32*K + k0, la + p*4096);
      gload16(gb + (size_t)p*32*K + k0, lb + p*4096);
    }
    __syncthreads();
    #pragma unroll
    for (int t=0;t<2;t++) {
      bf16x8 af[4], bfr[4];
      #pragma unroll
      for (int mi=0;mi<4;mi++)
        af[mi] = *reinterpret_cast<const bf16x8*>(lA + (wr*64+mi*16+lr)*128 + t*64 + lg*16);
      #pragma unroll
      for (int ni=0;ni<4;ni++)
        bfr[ni] = *reinterpret_cast<const bf16x8*>(lB + (wc*64+ni*16+lr)*128 + t*64 + lg*16);
      #pragma unroll
      for (int mi=0;mi<4;mi++)
        #pragma unroll
        for (int ni=0;ni<4;ni++)
          acc[mi][ni] = __builtin_amdgcn_mfma_f32_16x16x32_bf16(af[mi], bfr[ni], acc[mi][ni], 0, 0, 0);
    }
  }

  if (!QKV || n0 < 2*D_MODEL) {
    #pragma unroll
    for (int mi=0;mi<4;mi++)
      #pragma unroll
      for (int ni=0;ni<4;ni++)
        #pragma unroll
        for (int r=0;r<4;r++) {
          int m = m0 + wr*64 + mi*16 + lg*4 + r;
          int n = n0 + wc*64 + ni*16 + lr;
          C[(size_t)m*N + n] = (OutT)acc[mi][ni][r];
        }
  } else {
    #pragma unroll
    for (int mi=0;mi<4;mi++)
      #pragma unroll
      for (int ni=0;ni<4;ni++)
        #pragma unroll
        for (int r=0;r<4;r++) {
          int m = m0 + wr*64 + mi*16 + lg*4 + r;
          int nl = n0 + wc*64 + ni*16 + lr - 2*D_MODEL;
          int h = nl >> 6, d = nl & 63;
          int bb = m >> 11, s = m & (SEQ-1);
          Vt[(((size_t)(bb*16 + h)*64 + d) << 11) + s] = (bf16_t)acc[mi][ni][r];
        }
  }
}

// ---------------- Flash causal attention, KV-split partials ----------------
// grid (48, B*H), block = 2 waves. Slot s (0..47): s<16 -> q-tile s, full KV
// range; s>=16 -> q-tile 16+(s-16)/2, half (s-16)&1 of its KV tiles.
// Each block writes an UNNORMALIZED partial: pO[slot] (64q x 64d bf16) +
// pML[slot][q] = (m, l). combine() merges the halves and normalizes.
__global__ __launch_bounds__(128, 2) void attn4(const bf16_t* __restrict__ QKV,
                                                const bf16_t* __restrict__ Vt,
                                                bf16_t* __restrict__ pO,
                                                float2* __restrict__ pML) {
  __shared__ __align__(16) char sK[2][64*128];
  __shared__ __align__(16) char sV[2][64*128];

  int bh = blockIdx.y;
  int b = bh >> 4, h = bh & 15;
  int tid = threadIdx.x, w = tid>>6, lane = tid&63;
  int q32 = lane & 31, hi = lane >> 5;

  int s = 47 - (int)blockIdx.x;        // heavy (split) slots dispatch first
  int qt, t0, t1;
  if (s < 16) { qt = s; t0 = 0; t1 = qt + 1; }
  else {
    int e = s - 16;
    qt = 16 + (e >> 1);
    int n = qt + 1, h0 = (n + 1) >> 1;
    t0 = (e & 1) ? h0 : 0;
    t1 = (e & 1) ? n  : h0;
  }
  int slot = bh*48 + s;

  const bf16_t* Kb = QKV + D_MODEL;
  const bf16_t* Vb = Vt + (size_t)bh*64*SEQ;

  int rsub = lane >> 3;                 // 0..7 within 8-row chunk
  int sg   = (lane&7) ^ rsub;           // inverse-swizzled slot

  int qw0 = qt*64 + w*32;
  int qg  = qw0 + q32;

  // Q fragments: lane q32 = column q; qf[ds] covers dims ds*16 + hi*8 ..+8
  bf16x8 qf[4];
  const bf16_t* qrow = QKV + (size_t)(b*SEQ + qw0 + q32)*NQKV + h*64 + hi*8;
  #pragma unroll
  for (int d=0; d<4; d++) qf[d] = *reinterpret_cast<const bf16x8*>(qrow + d*16);

  f32x16 O0 = (f32x16)0.0f, O1 = (f32x16)0.0f;
  float mrun = NEG_BIG, lrun = 0.f;

  // stage tile t0 into buf 0: wave w stages rows w*32..w*32+31 of K and V
  #pragma unroll
  for (int c=0;c<4;c++) {
    int rr = w*32 + 8*c + rsub;
    gload16(Kb + (size_t)(b*SEQ + t0*64 + rr)*NQKV + h*64 + sg*8,
            sK[0] + (w*32 + 8*c)*128 + lane*16);
    gload16(Vb + (size_t)rr*SEQ + t0*64 + sg*8,
            sV[0] + (w*32 + 8*c)*128 + lane*16);
  }
  __syncthreads();

  for (int ti = t0; ti < t1; ++ti) {
    int cur = (ti - t0) & 1;
    if (ti + 1 < t1) {
      int k0s = (ti+1)*64;
      #pragma unroll
      for (int c=0;c<4;c++) {
        int rr = w*32 + 8*c + rsub;
        gload16(Kb + (size_t)(b*SEQ + k0s + rr)*NQKV + h*64 + sg*8,
                sK[cur^1] + (w*32 + 8*c)*128 + lane*16);
        gload16(Vb + (size_t)rr*SEQ + k0s + sg*8,
                sV[cur^1] + (w*32 + 8*c)*128 + lane*16);
      }
    }

    int k0 = ti*64;

    // S^T = K * Q^T : p0 = keys 0..31, p1 = keys 32..63
    f32x16 p0 = (f32x16)0.0f, p1 = (f32x16)0.0f;
    __builtin_amdgcn_s_setprio(1);
    #pragma unroll
    for (int ds=0; ds<4; ds++) {
      bf16x8 k0f = *reinterpret_cast<const bf16x8*>(sK[cur] + swz128(q32,    ds*32 + hi*16));
      bf16x8 k1f = *reinterpret_cast<const bf16x8*>(sK[cur] + swz128(32+q32, ds*32 + hi*16));
      p0 = __builtin_amdgcn_mfma_f32_32x32x16_bf16(k0f, qf[ds], p0, 0, 0, 0);
      p1 = __builtin_amdgcn_mfma_f32_32x32x16_bf16(k1f, qf[ds], p1, 0, 0, 0);
    }
    __builtin_amdgcn_s_setprio(0);

    // causal mask: wave-uniform branch, only the diagonal tile pays
    if (ti == qt) {
      #pragma unroll
      for (int r=0; r<16; r++) {
        int kg = k0 + (r&3) + 8*(r>>2) + 4*hi;
        if (kg      > qg) p0[r] = NEG_BIG;
        if (kg + 32 > qg) p1[r] = NEG_BIG;
      }
    }

    // tree row-max (dep chain ~log2(32))
    float mx[8];
    #pragma unroll
    for (int r=0;r<8;r++) mx[r] = fmaxf(fmaxf(p0[r],p0[r+8]), fmaxf(p1[r],p1[r+8]));
    #pragma unroll
    for (int st=4; st>0; st>>=1)
      #pragma unroll
      for (int r=0;r<st;r++) mx[r] = fmaxf(mx[r], mx[r+st]);
    float mt   = fmaxf(mx[0], __shfl_xor(mx[0], 32, 64));
    float mnew = fmaxf(mrun, mt);
    float alpha = exp2f(mrun - mnew);
    #pragma unroll
    for (int r=0; r<16; r++) {
      p0[r] = exp2f(p0[r] - mnew);
      p1[r] = exp2f(p1[r] - mnew);
    }
    // tree row-sum
    float sx[8];
    #pragma unroll
    for (int r=0;r<8;r++) sx[r] = (p0[r]+p0[r+8]) + (p1[r]+p1[r+8]);
    #pragma unroll
    for (int st=4; st>0; st>>=1)
      #pragma unroll
      for (int r=0;r<st;r++) sx[r] += sx[r+st];
    float stot = sx[0] + __shfl_xor(sx[0], 32, 64);
    lrun = lrun*alpha + stot;
    mrun = mnew;
    O0 *= alpha; O1 *= alpha;

    // pack P -> bf16 and redistribute halves (T12)
    u32 pk0[8], pk1[8];
    #pragma unroll
    for (int i2=0; i2<8; i2++) {
      pk0[i2] = cvtpk_bf16(p0[2*i2], p0[2*i2+1]);
      pk1[i2] = cvtpk_bf16(p1[2*i2], p1[2*i2+1]);
    }
    plswap(pk0[0], pk0[2]); plswap(pk0[1], pk0[3]);
    plswap(pk0[4], pk0[6]); plswap(pk0[5], pk0[7]);
    plswap(pk1[0], pk1[2]); plswap(pk1[1], pk1[3]);
    plswap(pk1[4], pk1[6]); plswap(pk1[5], pk1[7]);

    bf16x8 pa[4];
    pa[0] = __builtin_bit_cast(bf16x8, (u32x4v){pk0[0],pk0[1],pk0[2],pk0[3]});
    pa[1] = __builtin_bit_cast(bf16x8, (u32x4v){pk0[4],pk0[5],pk0[6],pk0[7]});
    pa[2] = __builtin_bit_cast(bf16x8, (u32x4v){pk1[0],pk1[1],pk1[2],pk1[3]});
    pa[3] = __builtin_bit_cast(bf16x8, (u32x4v){pk1[4],pk1[5],pk1[6],pk1[7]});

    // O^T += V^T * P^T
    __builtin_amdgcn_s_setprio(1);
    #pragma unroll
    for (int ks=0; ks<4; ks++) {
      bf16x8 v0 = *reinterpret_cast<const bf16x8*>(sV[cur] + swz128(q32,    ks*32 + hi*16));
      bf16x8 v1 = *reinterpret_cast<const bf16x8*>(sV[cur] + swz128(32+q32, ks*32 + hi*16));
      O0 = __builtin_amdgcn_mfma_f32_32x32x16_bf16(v0, pa[ks], O0, 0, 0, 0);
      O1 = __builtin_amdgcn_mfma_f32_32x32x16_bf16(v1, pa[ks], O1, 0, 0, 0);
    }
    __builtin_amdgcn_s_setprio(0);

    __syncthreads();   // drains prefetch vmcnt + joins waves
  }

  // epilogue: write UNNORMALIZED partial O (bf16) + (m,l)
  bf16_t* prow = pO + ((size_t)slot*4096 + (w*32 + q32)*64);
  #pragma unroll
  for (int rg=0; rg<4; rg++) {
    int d0 = 8*rg + 4*hi;
    u32 a0 = cvtpk_bf16(O0[4*rg],   O0[4*rg+1]);
    u32 a1 = cvtpk_bf16(O0[4*rg+2], O0[4*rg+3]);
    *reinterpret_cast<u32x2v*>(prow + d0) = (u32x2v){a0, a1};
    u32 b0 = cvtpk_bf16(O1[4*rg],   O1[4*rg+1]);
    u32 b1 = cvtpk_bf16(O1[4*rg+2], O1[4*rg+3]);
    *reinterpret_cast<u32x2v*>(prow + 32 + d0) = (u32x2v){b0, b1};
  }
  if (hi == 0)
    pML[slot*64 + w*32 + q32] = make_float2(mrun, lrun);
}

// ---------------- combine partials -> Of ----------------
// grid (32 qtiles, 32 bh), 256 thr; thread t: q = t>>2, d0 = (t&3)*16.
__global__ __launch_bounds__(256) void combine(const bf16_t* __restrict__ pO,
                                               const float2* __restrict__ pML,
                                               bf16_t* __restrict__ Of) {
  int qt = blockIdx.x, bh = blockIdx.y;
  int b = bh >> 4, h = bh & 15;
  int t = threadIdx.x;
  int q = t >> 2, d0 = (t & 3) * 16;
  bf16x8 r0, r1;
  if (qt < 16) {
    int slot = bh*48 + qt;
    float2 ml = pML[slot*64 + q];
    float inv = 1.0f / ml.y;
    const bf16x8* src = reinterpret_cast<const bf16x8*>(pO + (size_t)slot*4096 + q*64 + d0);
    bf16x8 o0 = src[0], o1 = src[1];
    #pragma unroll
    for (int i=0;i<8;i++) {
      r0[i] = (bf16_t)((float)o0[i]*inv);
      r1[i] = (bf16_t)((float)o1[i]*inv);
    }
  } else {
    int s0 = bh*48 + 16 + (qt-16)*2;
    float2 mlA = pML[s0*64 + q];
    float2 mlB = pML[(s0+1)*64 + q];
    float m  = fmaxf(mlA.x, mlB.x);
    float a0 = exp2f(mlA.x - m), a1 = exp2f(mlB.x - m);
    float inv = 1.0f / (a0*mlA.y + a1*mlB.y);
    a0 *= inv; a1 *= inv;
    const bf16x8* sA = reinterpret_cast<const bf16x8*>(pO + (size_t)s0*4096 + q*64 + d0);
    const bf16x8* sB = reinterpret_cast<const bf16x8*>(pO + (size_t)(s0+1)*4096 + q*64 + d0);
    bf16x8 oa0 = sA[0], oa1 = sA[1], ob0 = sB[0], ob1 = sB[1];
    #pragma unroll
    for (int i=0;i<8;i++) {
      r0[i] = (bf16_t)(a0*(float)oa0[i] + a1*(float)ob0[i]);
      r1[i] = (bf16_t)(a0*(float)oa1[i] + a1*(float)ob1[i]);
    }
  }
  bf16x8* dst = reinterpret_cast<bf16x8*>(Of + ((size_t)(b*SEQ) + qt*64 + q)*D_MODEL + h*64 + d0);
  dst[0] = r0; dst[1] = r1;
}

// ---------------- launch ----------------
// Workspace lifetimes:
//   [ 0,  8) MB xb   (phases 1-2)  -> pO head  (attn/combine)
//   [ 8, 14) MB wqkv (phases 1-2)  -> pO tail + pML
//   [14, 16) MB wob  (all phases)
//   [16, 40) MB QKV  (gemm->attn)
//   [40, 48) MB Vtb  (gemm->attn)  -> Of (combine->out-gemm)
extern "C" void kernel_launch(void* const* d_in, const int* in_sizes, int n_in,
                              void* d_out, int out_size, void* d_ws, size_t ws_size,
                              hipStream_t stream) {
  const float* x   = (const float*)d_in[0];
  const int*   pos = (const int*)  d_in[1];
  const float* wq  = (const float*)d_in[2];
  const float* wk  = (const float*)d_in[3];
  const float* wv  = (const float*)d_in[4];
  const float* wo  = (const float*)d_in[5];
  float* out = (float*)d_out;

  char* ws = (char*)d_ws;
  bf16_t* xb   = (bf16_t*)(ws);
  bf16_t* wqkv = (bf16_t*)(ws + ( 8u<<20));
  bf16_t* wob  = (bf16_t*)(ws + (14u<<20));
  bf16_t* QKV  = (bf16_t*)(ws + (16u<<20));
  bf16_t* Vtb  = (bf16_t*)(ws + (40u<<20));
  bf16_t* pO   = (bf16_t*)(ws);                 // 1536*4096*2B = 12 MB
  float2* pML  = (float2*)(ws + (12u<<20));     // 1536*64*8B = 768 KB
  bf16_t* Of   = (bf16_t*)(ws + (40u<<20));     // overlays dead Vtb

  cvt_x<<<NTOK*D_MODEL/1024, 256, 0, stream>>>(x, xb);
  cvt_w<<<4*D_MODEL*D_MODEL/1024, 256, 0, stream>>>(wq, wk, wv, wo, wqkv, wob);

  dim3 gqkv(NQKV/128, NTOK/128);
  gemm_bt<bf16_t, true><<<gqkv, 256, 0, stream>>>(xb, wqkv, QKV, Vtb, NTOK, NQKV, D_MODEL);

  rope_qk<<<NTOK*NUM_HEADS*32/256, 256, 0, stream>>>(QKV, pos);

  dim3 gattn(48, BATCH*NUM_HEADS);
  attn4<<<gattn, 128, 0, stream>>>(QKV, Vtb, pO, pML);

  dim3 gcomb(SEQ/64, BATCH*NUM_HEADS);
  combine<<<gcomb, 256, 0, stream>>>(pO, pML, Of);

  dim3 gout(D_MODEL/128, NTOK/128);
  gemm_bt<float, false><<<gout, 256, 0, stream>>>(Of, wob, out, nullptr, NTOK, D_MODEL, D_MODEL);
}